// Round 2
// 9566.333 us; speedup vs baseline: 1.4295x; 1.4295x over previous
//
#include <hip/hip_runtime.h>
#include <cmath>

// Problem constants (match reference file)
#define B  64
#define S  100
#define H  1024
#define H2 2048
#define H3 3072
#define V  32000
#define LSTEPS 50

// d_out layout (floats): logits [B,L,V] | hT [B,H] | attn [B,L,S]
#define OUT_HT   102400000LL          // B*L*V
#define OUT_ATTN 102465536LL          // + B*H

// workspace layout (float offsets)
#define OFF_UAK 0LL                   // B*S*H        = 6,553,600
#define OFF_QP  6553600LL             // 8*B*H        =   524,288
#define OFF_Q   7077888LL             // B*H          =    65,536
#define OFF_GIP 7143424LL             // 8*B*3H       = 1,572,864
#define OFF_GHP 8716288LL             // 8*B*3H       = 1,572,864
#define OFF_X   10289152LL            // B*3H         =   196,608
#define OFF_E   10485760LL            // B*S          =     6,400
#define OFF_H   10492160LL            // B*H          =    65,536
#define OFF_PK  10557696LL            // B u64 packed argmax (128 floats)
// NOTE: logits split-K partial c=1 (B*V = 2,048,000 floats) aliases
// OFF_GIP..  (gip/ghp are dead after k_gru each step).

// ---------------------------------------------------------------------------
// init: h = encoder_hidden[0], packed argmax = token 0
__global__ void k_init(const float* __restrict__ eh, float* __restrict__ h,
                       unsigned long long* __restrict__ packed) {
    int i = blockIdx.x * 256 + threadIdx.x;
    if (i < B * H) h[i] = eh[i];
    if (i < B) packed[i] = 0xFFFFFFFFull;   // key 0, ~idx=0xffffffff -> tok 0
}

// ---------------------------------------------------------------------------
// Fat GEMM: C[m,n] = sum_k A[m,k]*W[n,k] + bias[n]
// A:[M,K] row-major, W:[N,K] row-major. BM=128, BN=64, BK=16, 256 thr, 8x4/thr
// Double-buffered LDS. Used for UaK: M=6400 (b*s), N=1024, K=2048.
__global__ __launch_bounds__(256) void k_gemm_fat(
    const float* __restrict__ A, const float* __restrict__ W,
    const float* __restrict__ bias, float* __restrict__ C, int K, int N)
{
    __shared__ __align__(16) float As[2][16][132];   // [k][m], pad
    __shared__ __align__(16) float Ws[2][16][68];    // [k][n], pad
    const int tid = threadIdx.x;
    const int tn  = tid & 15;          // n = tn*4   (0..63)
    const int tm  = tid >> 4;          // m = tm*8   (0..127)
    const long m0 = (long)blockIdx.y * 128;
    const int  n0 = blockIdx.x * 64;

    // staging indices: A tile 128x16 -> 2 float4/thr, W tile 64x16 -> 1 float4/thr
    const int sam = tid >> 2, saq = (tid & 3) * 4;           // A row (i=0), k-slot
    const int swn = tid >> 2, swq = (tid & 3) * 4;           // W row, k-slot
    const float* Ap0 = A + (m0 + sam) * (long)K + saq;
    const float* Ap1 = A + (m0 + 64 + sam) * (long)K + saq;
    const float* Wp  = W + (long)(n0 + swn) * K + swq;

    float acc[8][4];
#pragma unroll
    for (int i = 0; i < 8; i++)
#pragma unroll
        for (int j = 0; j < 4; j++) acc[i][j] = 0.f;

    const int NIT = K >> 4;
    float4 ra0 = *(const float4*)(Ap0);
    float4 ra1 = *(const float4*)(Ap1);
    float4 rw  = *(const float4*)(Wp);
    As[0][saq+0][sam] = ra0.x; As[0][saq+1][sam] = ra0.y;
    As[0][saq+2][sam] = ra0.z; As[0][saq+3][sam] = ra0.w;
    As[0][saq+0][64+sam] = ra1.x; As[0][saq+1][64+sam] = ra1.y;
    As[0][saq+2][64+sam] = ra1.z; As[0][saq+3][64+sam] = ra1.w;
    Ws[0][swq+0][swn] = rw.x; Ws[0][swq+1][swn] = rw.y;
    Ws[0][swq+2][swn] = rw.z; Ws[0][swq+3][swn] = rw.w;
    __syncthreads();
    int cur = 0;
    for (int it = 0; it < NIT; ++it) {
        const bool pf = (it + 1 < NIT);
        if (pf) {
            long kn = (long)(it + 1) * 16;
            ra0 = *(const float4*)(Ap0 + kn);
            ra1 = *(const float4*)(Ap1 + kn);
            rw  = *(const float4*)(Wp + kn);
        }
#pragma unroll
        for (int kk = 0; kk < 16; kk++) {
            float4 a0 = *(const float4*)&As[cur][kk][tm * 8];
            float4 a1 = *(const float4*)&As[cur][kk][tm * 8 + 4];
            float4 wf = *(const float4*)&Ws[cur][kk][tn * 4];
            float a[8] = {a0.x,a0.y,a0.z,a0.w,a1.x,a1.y,a1.z,a1.w};
            float w[4] = {wf.x,wf.y,wf.z,wf.w};
#pragma unroll
            for (int i = 0; i < 8; i++)
#pragma unroll
                for (int j = 0; j < 4; j++)
                    acc[i][j] = fmaf(a[i], w[j], acc[i][j]);
        }
        if (pf) {
            int nb = cur ^ 1;
            As[nb][saq+0][sam] = ra0.x; As[nb][saq+1][sam] = ra0.y;
            As[nb][saq+2][sam] = ra0.z; As[nb][saq+3][sam] = ra0.w;
            As[nb][saq+0][64+sam] = ra1.x; As[nb][saq+1][64+sam] = ra1.y;
            As[nb][saq+2][64+sam] = ra1.z; As[nb][saq+3][64+sam] = ra1.w;
            Ws[nb][swq+0][swn] = rw.x; Ws[nb][swq+1][swn] = rw.y;
            Ws[nb][swq+2][swn] = rw.z; Ws[nb][swq+3][swn] = rw.w;
            __syncthreads();
            cur = nb;
        }
    }
#pragma unroll
    for (int i = 0; i < 8; i++) {
        long m = m0 + tm * 8 + i;
#pragma unroll
        for (int j = 0; j < 4; j++) {
            int n = n0 + tn * 4 + j;
            C[m * N + n] = acc[i][j] + bias[n];
        }
    }
}

// ---------------------------------------------------------------------------
// Skinny GEMM (M=64): C[m,n] = sum_{k chunk} A[m,k]*W[n,k]
// BN=128, BK=16, 256 thr, 8x4/thr, double-buffered LDS.
// nsplit>1: write partials [c][64][N]; nsplit==1: write C + bias.
__global__ __launch_bounds__(256) void k_gemm_skinny(
    const float* __restrict__ A, const float* __restrict__ W,
    const float* __restrict__ bias, float* __restrict__ C,
    int K, int N, long ldc, int nsplit)
{
    __shared__ __align__(16) float As[2][16][68];    // [k][m]
    __shared__ __align__(16) float Ws[2][16][132];   // [k][n]
    const int tid = threadIdx.x;
    const int tn  = tid & 31;          // n = tn*4 (0..127)
    const int tm  = tid >> 5;          // m = tm*8 (0..63)
    const int n0  = blockIdx.x * 128;
    const int Kc  = K / nsplit;
    const int kbeg = blockIdx.y * Kc;
    const int NIT = Kc >> 4;

    // staging: A tile 64x16 -> 1 float4/thr, W tile 128x16 -> 2 float4/thr
    const int sam = tid >> 2, saq = (tid & 3) * 4;
    const float* Ap  = A + (long)sam * K + kbeg + (tid & 3) * 4;
    const float* Wp0 = W + (long)(n0 + sam) * K + kbeg + (tid & 3) * 4;
    const float* Wp1 = W + (long)(n0 + 64 + sam) * K + kbeg + (tid & 3) * 4;

    float acc[8][4];
#pragma unroll
    for (int i = 0; i < 8; i++)
#pragma unroll
        for (int j = 0; j < 4; j++) acc[i][j] = 0.f;

    float4 ra  = *(const float4*)(Ap);
    float4 rw0 = *(const float4*)(Wp0);
    float4 rw1 = *(const float4*)(Wp1);
    As[0][saq+0][sam] = ra.x;  As[0][saq+1][sam] = ra.y;
    As[0][saq+2][sam] = ra.z;  As[0][saq+3][sam] = ra.w;
    Ws[0][saq+0][sam] = rw0.x; Ws[0][saq+1][sam] = rw0.y;
    Ws[0][saq+2][sam] = rw0.z; Ws[0][saq+3][sam] = rw0.w;
    Ws[0][saq+0][64+sam] = rw1.x; Ws[0][saq+1][64+sam] = rw1.y;
    Ws[0][saq+2][64+sam] = rw1.z; Ws[0][saq+3][64+sam] = rw1.w;
    __syncthreads();
    int cur = 0;
    for (int it = 0; it < NIT; ++it) {
        const bool pf = (it + 1 < NIT);
        if (pf) {
            long kn = (long)(it + 1) * 16;
            ra  = *(const float4*)(Ap + kn);
            rw0 = *(const float4*)(Wp0 + kn);
            rw1 = *(const float4*)(Wp1 + kn);
        }
#pragma unroll
        for (int kk = 0; kk < 16; kk++) {
            float4 a0 = *(const float4*)&As[cur][kk][tm * 8];
            float4 a1 = *(const float4*)&As[cur][kk][tm * 8 + 4];
            float4 wf = *(const float4*)&Ws[cur][kk][tn * 4];
            float a[8] = {a0.x,a0.y,a0.z,a0.w,a1.x,a1.y,a1.z,a1.w};
            float w[4] = {wf.x,wf.y,wf.z,wf.w};
#pragma unroll
            for (int i = 0; i < 8; i++)
#pragma unroll
                for (int j = 0; j < 4; j++)
                    acc[i][j] = fmaf(a[i], w[j], acc[i][j]);
        }
        if (pf) {
            int nb = cur ^ 1;
            As[nb][saq+0][sam] = ra.x;  As[nb][saq+1][sam] = ra.y;
            As[nb][saq+2][sam] = ra.z;  As[nb][saq+3][sam] = ra.w;
            Ws[nb][saq+0][sam] = rw0.x; Ws[nb][saq+1][sam] = rw0.y;
            Ws[nb][saq+2][sam] = rw0.z; Ws[nb][saq+3][sam] = rw0.w;
            Ws[nb][saq+0][64+sam] = rw1.x; Ws[nb][saq+1][64+sam] = rw1.y;
            Ws[nb][saq+2][64+sam] = rw1.z; Ws[nb][saq+3][64+sam] = rw1.w;
            __syncthreads();
            cur = nb;
        }
    }
    if (nsplit > 1) {
        float* Cp = C + (long)blockIdx.y * 64 * N;
#pragma unroll
        for (int i = 0; i < 8; i++)
#pragma unroll
            for (int j = 0; j < 4; j++)
                Cp[(long)(tm * 8 + i) * N + n0 + tn * 4 + j] = acc[i][j];
    } else {
#pragma unroll
        for (int i = 0; i < 8; i++)
#pragma unroll
            for (int j = 0; j < 4; j++) {
                int n = n0 + tn * 4 + j;
                C[(long)(tm * 8 + i) * ldc + n] = acc[i][j] + bias[n];
            }
    }
}

// ---------------------------------------------------------------------------
// Logits GEMM: A=h [64][1024], W=W_out [V][1024]. 128 thr, 8x8/thr, BN=128,
// split-K=2 (Kc=512, 32 iters), double-buffered. blockIdx.y==0 -> C0 (out,
// ldc=L*V), ==1 -> C1 (partial, ldc=V). No bias (added in reduce).
__global__ __launch_bounds__(128) void k_gemm_out(
    const float* __restrict__ A, const float* __restrict__ W,
    float* __restrict__ C0, float* __restrict__ C1)
{
    __shared__ __align__(16) float As[2][16][68];    // [k][m] 64 m
    __shared__ __align__(16) float Ws[2][16][132];   // [k][n] 128 n
    const int tid = threadIdx.x;
    const int n0  = blockIdx.x * 128;
    const int kbeg = blockIdx.y * 512;

    // staging: A 64x16 = 2 float4/thr (same row, 8 consecutive k)
    const int sam = tid >> 1;
    const int sak = (tid & 1) * 8;
    const float* Ap = A + (long)sam * H + kbeg + sak;
    // W 128x16 = 4 float4/thr: rows tid>>2 + 32i, k-slot (tid&3)*4
    const int swn = tid >> 2;
    const int swk = (tid & 3) * 4;
    const float* Wp = W + (long)(n0 + swn) * H + kbeg + swk;

    const int m0 = (tid >> 4) * 8;     // 0..56
    const int nbh = (tid & 15) * 4;    // 0..60

    float acc[8][8];
#pragma unroll
    for (int i = 0; i < 8; i++)
#pragma unroll
        for (int j = 0; j < 8; j++) acc[i][j] = 0.f;

    float4 ra0 = *(const float4*)(Ap);
    float4 ra1 = *(const float4*)(Ap + 4);
    float4 rw[4];
#pragma unroll
    for (int i = 0; i < 4; i++)
        rw[i] = *(const float4*)(Wp + (long)(32 * i) * H);

    As[0][sak+0][sam] = ra0.x; As[0][sak+1][sam] = ra0.y;
    As[0][sak+2][sam] = ra0.z; As[0][sak+3][sam] = ra0.w;
    As[0][sak+4][sam] = ra1.x; As[0][sak+5][sam] = ra1.y;
    As[0][sak+6][sam] = ra1.z; As[0][sak+7][sam] = ra1.w;
#pragma unroll
    for (int i = 0; i < 4; i++) {
        Ws[0][swk+0][swn+32*i] = rw[i].x; Ws[0][swk+1][swn+32*i] = rw[i].y;
        Ws[0][swk+2][swn+32*i] = rw[i].z; Ws[0][swk+3][swn+32*i] = rw[i].w;
    }
    __syncthreads();
    int cur = 0;
    for (int it = 0; it < 32; ++it) {
        const bool pf = (it + 1 < 32);
        if (pf) {
            long kn = (long)(it + 1) * 16;
            ra0 = *(const float4*)(Ap + kn);
            ra1 = *(const float4*)(Ap + kn + 4);
#pragma unroll
            for (int i = 0; i < 4; i++)
                rw[i] = *(const float4*)(Wp + (long)(32 * i) * H + kn);
        }
#pragma unroll
        for (int kk = 0; kk < 16; kk++) {
            float4 a0 = *(const float4*)&As[cur][kk][m0];
            float4 a1 = *(const float4*)&As[cur][kk][m0 + 4];
            float4 w0 = *(const float4*)&Ws[cur][kk][nbh];
            float4 w1 = *(const float4*)&Ws[cur][kk][64 + nbh];
            float a[8] = {a0.x,a0.y,a0.z,a0.w,a1.x,a1.y,a1.z,a1.w};
            float w[8] = {w0.x,w0.y,w0.z,w0.w,w1.x,w1.y,w1.z,w1.w};
#pragma unroll
            for (int i = 0; i < 8; i++)
#pragma unroll
                for (int j = 0; j < 8; j++)
                    acc[i][j] = fmaf(a[i], w[j], acc[i][j]);
        }
        if (pf) {
            int nb = cur ^ 1;
            As[nb][sak+0][sam] = ra0.x; As[nb][sak+1][sam] = ra0.y;
            As[nb][sak+2][sam] = ra0.z; As[nb][sak+3][sam] = ra0.w;
            As[nb][sak+4][sam] = ra1.x; As[nb][sak+5][sam] = ra1.y;
            As[nb][sak+6][sam] = ra1.z; As[nb][sak+7][sam] = ra1.w;
#pragma unroll
            for (int i = 0; i < 4; i++) {
                Ws[nb][swk+0][swn+32*i] = rw[i].x; Ws[nb][swk+1][swn+32*i] = rw[i].y;
                Ws[nb][swk+2][swn+32*i] = rw[i].z; Ws[nb][swk+3][swn+32*i] = rw[i].w;
            }
            __syncthreads();
            cur = nb;
        }
    }
    float* Cp; long ldc;
    if (blockIdx.y == 0) { Cp = C0; ldc = (long)LSTEPS * V; }
    else                 { Cp = C1; ldc = V; }
#pragma unroll
    for (int i = 0; i < 8; i++) {
        float4 v0 = make_float4(acc[i][0], acc[i][1], acc[i][2], acc[i][3]);
        float4 v1 = make_float4(acc[i][4], acc[i][5], acc[i][6], acc[i][7]);
        float* row = Cp + (long)(m0 + i) * ldc + n0;
        *(float4*)(row + nbh) = v0;
        *(float4*)(row + 64 + nbh) = v1;
    }
}

// ---------------------------------------------------------------------------
// logits reduce: out = c0(out) + c1(P1) + bias; fused per-block argmax ->
// atomicMax on packed (float-key<<32 | ~idx). grid (32 n-chunks, 64 b).
__global__ __launch_bounds__(256) void k_out_reduce(
    const float* __restrict__ P1, const float* __restrict__ bias,
    float* __restrict__ out, unsigned long long* __restrict__ packed, int t)
{
    __shared__ float bv[256];
    __shared__ int   bi[256];
    const int b = blockIdx.y, tid = threadIdx.x;
    const int n = blockIdx.x * 1024 + tid * 4;
    float best = -1e38f; int besti = 0x7fffffff;
    if (n < V) {
        float* o = out + (long)b * LSTEPS * V + (long)t * V + n;
        float4 c0 = *(const float4*)o;
        float4 p1 = *(const float4*)(P1 + (long)b * V + n);
        float4 bs = *(const float4*)(bias + n);
        float4 r;
        r.x = c0.x + p1.x + bs.x; r.y = c0.y + p1.y + bs.y;
        r.z = c0.z + p1.z + bs.z; r.w = c0.w + p1.w + bs.w;
        *(float4*)o = r;
        float vals[4] = {r.x, r.y, r.z, r.w};
#pragma unroll
        for (int j = 0; j < 4; j++)
            if (vals[j] > best) { best = vals[j]; besti = n + j; }
    }
    bv[tid] = best; bi[tid] = besti; __syncthreads();
    for (int s2 = 128; s2 > 0; s2 >>= 1) {
        if (tid < s2) {
            float ov = bv[tid + s2]; int oi = bi[tid + s2];
            if (ov > bv[tid] || (ov == bv[tid] && oi < bi[tid])) {
                bv[tid] = ov; bi[tid] = oi;
            }
        }
        __syncthreads();
    }
    if (tid == 0) {
        unsigned u = __float_as_uint(bv[0]);
        unsigned key = (u & 0x80000000u) ? ~u : (u | 0x80000000u);
        unsigned long long pk =
            ((unsigned long long)key << 32) | (unsigned)(~bi[0]);
        atomicMax(packed + b, pk);
    }
}

// ---------------------------------------------------------------------------
// q reduce: q[b,i] = sum_c qp[c][b,i] + Wa_b[i]      (65536 threads)
__global__ void k_qreduce(const float* __restrict__ qp,
                          const float* __restrict__ Wa_b, float* __restrict__ q) {
    int i = blockIdx.x * 256 + threadIdx.x;
    float s = Wa_b[i & (H - 1)];
#pragma unroll
    for (int c = 0; c < 8; c++) s += qp[(long)c * (B * H) + i];
    q[i] = s;
}

// ---------------------------------------------------------------------------
// score: e[b,s] = sum_h Va[h]*tanh(q[b,h] + UaK[b,s,h]) + Va_b. wave per (b,s).
__global__ __launch_bounds__(256) void k_score(
    const float* __restrict__ UaK, const float* __restrict__ q,
    const float* __restrict__ Va, const float* __restrict__ Va_b,
    float* __restrict__ e)
{
    int wid  = blockIdx.x * 4 + (threadIdx.x >> 6);   // 0..6399 == b*S+s
    int lane = threadIdx.x & 63;
    int b = wid / S;
    const float* u  = UaK + (long)wid * H;
    const float* qb = q + (long)b * H;
    float acc = 0.f;
#pragma unroll
    for (int i = 0; i < 4; i++) {
        int idx = i * 256 + lane * 4;
        float4 uv = *(const float4*)(u + idx);
        float4 qv = *(const float4*)(qb + idx);
        float4 vv = *(const float4*)(Va + idx);
        acc += vv.x * tanhf(qv.x + uv.x);
        acc += vv.y * tanhf(qv.y + uv.y);
        acc += vv.z * tanhf(qv.z + uv.z);
        acc += vv.w * tanhf(qv.w + uv.w);
    }
#pragma unroll
    for (int m = 32; m > 0; m >>= 1) acc += __shfl_xor(acc, m, 64);
    if (lane == 0) e[wid] = acc + Va_b[0];
}

// ---------------------------------------------------------------------------
// softmax over S + ctx chunk + emb gather. grid (4 chunks of 512 dims, 64 b).
// Token decoded from packed argmax word (no separate argmax kernel).
__global__ __launch_bounds__(256) void k_ctx(
    const float* __restrict__ e, const float* __restrict__ enc,
    const float* __restrict__ emb, const unsigned long long* __restrict__ packed,
    float* __restrict__ x, float* __restrict__ out_attn, int t)
{
    __shared__ float sw[128];
    __shared__ float red[256];
    const int c = blockIdx.x, b = blockIdx.y, tid = threadIdx.x;
    float v = (tid < S) ? e[b * S + tid] : -1e30f;
    red[tid] = v; __syncthreads();
    for (int s2 = 128; s2 > 0; s2 >>= 1) {
        if (tid < s2) red[tid] = fmaxf(red[tid], red[tid + s2]);
        __syncthreads();
    }
    float mx = red[0]; __syncthreads();
    float p = (tid < S) ? expf(v - mx) : 0.f;
    red[tid] = p; __syncthreads();
    for (int s2 = 128; s2 > 0; s2 >>= 1) {
        if (tid < s2) red[tid] += red[tid + s2];
        __syncthreads();
    }
    float inv = 1.f / red[0];
    if (tid < S) {
        float wv = p * inv;
        sw[tid] = wv;
        if (c == 0) out_attn[((long)b * LSTEPS + t) * S + tid] = wv;
    }
    __syncthreads();

    // ctx chunk: columns [c*512, c*512+512), float2 per thread
    const float* ep = enc + (long)b * S * H2 + c * 512 + tid * 2;
    float2 acc; acc.x = 0.f; acc.y = 0.f;
#pragma unroll 4
    for (int s = 0; s < S; s++) {
        float2 ev = *(const float2*)(ep + (long)s * H2);
        float wv = sw[s];
        acc.x = fmaf(wv, ev.x, acc.x);
        acc.y = fmaf(wv, ev.y, acc.y);
    }
    *(float2*)(x + (long)b * H3 + H + c * 512 + tid * 2) = acc;

    if (c < 2) {   // emb half: x[b][0:1024]
        int tokb = (int)(~(unsigned)(packed[b]));
        const float* er = emb + (long)tokb * H + c * 512 + tid * 2;
        *(float2*)(x + (long)b * H3 + c * 512 + tid * 2) = *(const float2*)er;
    }
}

// ---------------------------------------------------------------------------
// GRU combine: reduce split-K partials of gi/gh, gates, update h, emit hT.
// Also re-arms packed[b] for this step's argmax (runs before k_gemm_out).
__global__ void k_gru(const float* __restrict__ gip, const float* __restrict__ ghp,
                      const float* __restrict__ b_ih, const float* __restrict__ b_hh,
                      float* __restrict__ h, float* __restrict__ out_ht,
                      unsigned long long* __restrict__ packed)
{
    int idx = blockIdx.x * 256 + threadIdx.x;   // < B*H
    int b = idx >> 10, i = idx & (H - 1);
    float ir = b_ih[i], iz = b_ih[H + i], in_ = b_ih[H2 + i];
    float hr = b_hh[i], hz = b_hh[H + i], hn = b_hh[H2 + i];
#pragma unroll
    for (int c = 0; c < 8; c++) {
        const float* gp = gip + ((long)c * B + b) * H3;
        ir += gp[i]; iz += gp[H + i]; in_ += gp[H2 + i];
        const float* hp = ghp + ((long)c * B + b) * H3;
        hr += hp[i]; hz += hp[H + i]; hn += hp[H2 + i];
    }
    float r = 1.f / (1.f + expf(-(ir + hr)));
    float z = 1.f / (1.f + expf(-(iz + hz)));
    float n = tanhf(in_ + r * hn);
    float hv = h[idx];
    float hnew = (1.f - z) * n + z * hv;
    h[idx] = hnew;
    out_ht[idx] = hnew;
    if (idx < B) packed[idx] = 0ull;   // re-arm argmax accumulator
}

// ---------------------------------------------------------------------------
extern "C" void kernel_launch(void* const* d_in, const int* in_sizes, int n_in,
                              void* d_out_, int out_size, void* d_ws, size_t ws_size,
                              hipStream_t stream)
{
    const float* enc   = (const float*)d_in[0];
    const float* eh    = (const float*)d_in[1];
    // d_in[2] = max_len (50, hardcoded as LSTEPS)
    const float* emb   = (const float*)d_in[3];
    const float* Wa_w  = (const float*)d_in[4];
    const float* Wa_b  = (const float*)d_in[5];
    const float* Ua_w  = (const float*)d_in[6];
    const float* Ua_b  = (const float*)d_in[7];
    const float* Va_w  = (const float*)d_in[8];
    const float* Va_b  = (const float*)d_in[9];
    const float* W_ih  = (const float*)d_in[10];
    const float* W_hh  = (const float*)d_in[11];
    const float* b_ih  = (const float*)d_in[12];
    const float* b_hh  = (const float*)d_in[13];
    const float* W_out = (const float*)d_in[14];
    const float* b_out = (const float*)d_in[15];
    float* out = (float*)d_out_;
    float* ws  = (float*)d_ws;

    float* UaK = ws + OFF_UAK;
    float* qp  = ws + OFF_QP;
    float* q   = ws + OFF_Q;
    float* gip = ws + OFF_GIP;
    float* ghp = ws + OFF_GHP;
    float* x   = ws + OFF_X;
    float* e   = ws + OFF_E;
    float* h   = ws + OFF_H;
    unsigned long long* packed = (unsigned long long*)(ws + OFF_PK);
    float* P1  = ws + OFF_GIP;   // logits split-K partial, aliases gip/ghp

    k_init<<<dim3(256), dim3(256), 0, stream>>>(eh, h, packed);
    // UaK = enc @ Ua_w^T + Ua_b : M=6400, N=1024, K=2048
    k_gemm_fat<<<dim3(H / 64, (B * S) / 128), dim3(256), 0, stream>>>(
        enc, Ua_w, Ua_b, UaK, H2, H);

    for (int t = 0; t < LSTEPS; t++) {
        // q = h @ Wa_w^T (+Wa_b in reduce): N=1024, K=1024, splitK=8
        k_gemm_skinny<<<dim3(H / 128, 8), dim3(256), 0, stream>>>(
            h, Wa_w, nullptr, qp, H, H, (long)H, 8);
        k_qreduce<<<dim3(B * H / 256), dim3(256), 0, stream>>>(qp, Wa_b, q);
        k_score<<<dim3(B * S / 4), dim3(256), 0, stream>>>(UaK, q, Va_w, Va_b, e);
        k_ctx<<<dim3(4, B), dim3(256), 0, stream>>>(
            e, enc, emb, packed, x, out + OUT_ATTN, t);
        // gi = x @ W_ih^T : N=3072, K=3072, splitK=8
        k_gemm_skinny<<<dim3(H3 / 128, 8), dim3(256), 0, stream>>>(
            x, W_ih, nullptr, gip, H3, H3, (long)H3, 8);
        // gh = h @ W_hh^T : N=3072, K=1024, splitK=8
        k_gemm_skinny<<<dim3(H3 / 128, 8), dim3(256), 0, stream>>>(
            h, W_hh, nullptr, ghp, H, H3, (long)H3, 8);
        k_gru<<<dim3(B * H / 256), dim3(256), 0, stream>>>(
            gip, ghp, b_ih, b_hh, h, out + OUT_HT, packed);
        // logits = h_new @ W_out^T (bias+reduce+argmax fused in k_out_reduce)
        k_gemm_out<<<dim3(V / 128, 2), dim3(128), 0, stream>>>(
            h, W_out, out + (long)t * V, P1);
        k_out_reduce<<<dim3(32, B), dim3(256), 0, stream>>>(
            P1, b_out, out, packed, t);
    }
}